// Round 8
// baseline (180.262 us; speedup 1.0000x reference)
//
#include <hip/hip_runtime.h>
#include <hip/hip_bf16.h>

// Rounds 0-18 established: fp32 inputs (inline detector), fp32 out, bf16
// MFMA everywhere. R10: loads issued just before a __syncthreads are
// DEFEATED (barrier drains vmcnt(0)) — unless issued a full compute-phase
// earlier (R18). R12: swapped-QK attn, lane-local softmax, exp2-domain,
// rescale-skip. R13: zero-LDS P path (sigma order). R14: 512-thr attn,
// shared staging, complementary pairing. R17 falsified barrier-theory but
// yielded vfrag (V pre-laid in MFMA frag order -> staging is linear copy).
// R18: vfrag via gload16 dbuf + O^T PV (lane-local alpha/l/epilogue):
// 186.5 -> 176.7 (best).
// R19 (this round): finish the recipe.
//  - kfrag: gemm1 writes K in linear fragment order with bank-XOR
//    pre-applied (col ^= (t&3)<<3; multiple-of-8 so b128 reads stay
//    contiguous). attn stages K via gload16 (1 instr/wave/tile), reads
//    with the XOR -> 2 lanes/bank = free (m136). All staging now pure
//    async gload -> ONE barrier per s-tile (was 2): the barrier's vmcnt
//    drain IS the data-ready signal; buf[cur^1] is only written by gloads
//    issued after the barrier proving all waves finished reading it.
//  - T1 XCD-chunked swizzle on both GEMMs (lid=(bid&7)*128+(bid>>3),
//    bijective at 1024): per-XCD set ~5MB/~3MB ~= L2 capacity (was 12MB).
// Pre-committed: flat +-3 -> structural floor, roofline next round.
#define B_  2
#define T_  2048
#define D_  1024
#define H_  16
#define DH_ 64
#define R_  32
#define BT_ (B_*T_)          // 4096
#define BH_ (B_*H_)          // 32

typedef unsigned short u16;
typedef unsigned int   u32;
typedef __attribute__((ext_vector_type(8))) short bhalf8;   // 8 bf16 = 4 VGPRs
typedef __attribute__((ext_vector_type(4))) float floatx4;  // MFMA C/D

// Workspace layout (bytes). Total ~38 MB.
#define WSB_FLAG  0
#define WSB_XB    256                        // bf16 x     (4096,1024)  8 MB
#define WSB_WCATT (WSB_XB    + 8388608)      // bf16 WcatT (2048,1024)  4 MB
#define WSB_QL    (WSB_WCATT + 4194304)      // bf16 (B,H,T,R)          4 MB
#define WSB_KF    (WSB_QL    + 4194304)      // bf16 kfrag (B,H,...)    4 MB
#define WSB_VT    (WSB_KF    + 4194304)      // bf16 vfrag (B,H,...)    8 MB
#define WSB_YB    (WSB_VT    + 8388608)      // bf16 y     (B,T,D)      8 MB
#define WSB_WOT   (WSB_YB    + 8388608)      // bf16 WoT   (1024,1024)  2 MB

#define NEG_ -1.0e30f

__device__ __forceinline__ float bfs(u16 s) {
    union { u32 i; float f; } w; w.i = ((u32)s) << 16; return w.f;
}
__device__ __forceinline__ u16 tob(float f) {
    __hip_bfloat16 h = __float2bfloat16(f);   // RNE
    return *(u16*)&h;
}
__device__ __forceinline__ u32 pack2(float a, float b) {
    return (u32)tob(a) | ((u32)tob(b) << 16);
}
// Direct global->LDS staging, 16B/lane. LDS base wave-uniform; HW writes
// base + lane*16. Global address is per-lane.
__device__ __forceinline__ void gload16(const u16* g, u16* l) {
    __builtin_amdgcn_global_load_lds(
        (const __attribute__((address_space(1))) void*)g,
        (__attribute__((address_space(3))) void*)l, 16, 0, 0);
}
// Inline dtype detect (1 = bf16, 0 = fp32) from first 2KB of x.
__device__ __forceinline__ int detect_isbf(const u32* __restrict__ xw, int lane) {
    int hits = 0;
    #pragma unroll
    for (int i = 0; i < 8; ++i) {
        const u32 w = xw[lane + i * 64];
        const u32 h = w & 0xFFFFu;
        const u32 e = (h >> 7) & 0xFFu;
        if (h == 0u || (e >= 100u && e <= 150u)) ++hits;
    }
    #pragma unroll
    for (int off = 32; off; off >>= 1) hits += __shfl_down(hits, off, 64);
    return __shfl(hits, 0, 64) >= 300;
}

// ---------------------------------------------------------------------------
// Kernel P: fused preprocessing (R17).
//  blocks 0..2047   : x -> xb bf16 (8 elems/thread)
//  blocks 2048..2303: transposing convert W_v slice of Wqkv -> WcatT[1024..]
//  blocks 2304..2559: transposing convert W_o -> WoT
//  blocks 2560..2687: fold via MFMA (scale incl 1/sqrt(32)*log2(e))
// ---------------------------------------------------------------------------
__global__ __launch_bounds__(256) void prep_kernel(
    const void* __restrict__ x, u16* __restrict__ xb,
    const void* __restrict__ Wqkv, const void* __restrict__ Wo,
    const void* __restrict__ Wq_lsr, const void* __restrict__ Wk_lsr,
    const void* __restrict__ core,
    u16* __restrict__ WcatT, u16* __restrict__ WoT)
{
    __shared__ __align__(16) u16 Bq[128 * 72];   // fold [n=d][k=dh]; also T-tile
    __shared__ __align__(16) u16 Bk[128 * 72];
    __shared__ __align__(16) u16 Aq[32 * 72];    // fold [m=r][k=dh]
    __shared__ __align__(16) u16 Ak[32 * 72];
    const int tid  = threadIdx.x;
    const int lane = tid & 63;
    const int isbf = detect_isbf((const u32*)x, lane);
    const int blk  = blockIdx.x;
    const int w    = tid >> 6;
    const int n16  = lane & 15;
    const int q4   = lane >> 4;

    if (blk < 2048) {
        const int e = blk * 256 + tid;           // over 524288 (x8 elems)
        if (isbf) {
            ((uint4*)xb)[e] = ((const uint4*)x)[e];
        } else {
            float4 a0 = ((const float4*)x)[2*e];
            float4 a1 = ((const float4*)x)[2*e + 1];
            uint4 o;
            o.x = pack2(a0.x, a0.y); o.y = pack2(a0.z, a0.w);
            o.z = pack2(a1.x, a1.y); o.w = pack2(a1.z, a1.w);
            ((uint4*)xb)[e] = o;
        }
        return;
    }

    if (blk < 2560) {
        // transposing convert, 64x64 tiles (uses Bq as scratch tile)
        int t = blk - 2048;
        const void* src; u16* dst; int srcStride, srcColOff, dstRowOff;
        if (t < 256) { src = Wqkv; dst = WcatT; srcStride = 3*D_; srcColOff = 2*D_; dstRowOff = 1024; }
        else { t -= 256; src = Wo; dst = WoT; srcStride = D_; srcColOff = 0; dstRowOff = 0; }
        const int j0 = (t & 15) * 64;
        const int i0 = (t >> 4) * 64;
        #pragma unroll
        for (int p = 0; p < 2; ++p) {
            const int e = tid + p * 256;
            const int r = e >> 3, ch = e & 7;
            if (isbf) {
                uint4 v = *(const uint4*)((const u16*)src + (size_t)(i0 + r) * srcStride + srcColOff + j0 + ch*8);
                *(uint4*)&Bq[r * 72 + ch*8] = v;
            } else {
                const float* s = (const float*)src + (size_t)(i0 + r) * srcStride + srcColOff + j0 + ch*8;
                float4 a0 = *(const float4*)s;
                float4 a1 = *(const float4*)(s + 4);
                uint4 o;
                o.x = pack2(a0.x, a0.y); o.y = pack2(a0.z, a0.w);
                o.z = pack2(a1.x, a1.y); o.w = pack2(a1.z, a1.w);
                *(uint4*)&Bq[r * 72 + ch*8] = o;
            }
        }
        __syncthreads();
        #pragma unroll
        for (int p = 0; p < 2; ++p) {
            const int e = tid + p * 256;
            const int c = e >> 3, ch = e & 7;
            u16 tmp[8];
            #pragma unroll
            for (int j = 0; j < 8; ++j) tmp[j] = Bq[(ch*8 + j) * 72 + c];
            *(uint4*)(dst + (size_t)(dstRowOff + j0 + c) * D_ + i0 + ch*8) = *(uint4*)tmp;
        }
        return;
    }

    // fold: per head h, Cq(32x1024) = Aq_h^T(32x64) @ Wq_h(64x1024)
    const int fb = blk - 2560;          // 0..127
    const int h  = fb & 15;
    const int d0 = (fb >> 4) * 128;

    #pragma unroll
    for (int p = 0; p < 8; ++p) {
        const int e  = tid + p * 256;
        const int r  = e & 31, dh = e >> 5;
        float aq, ak;
        if (isbf) {
            aq = bfs(((const u16*)Wq_lsr)[(h*DH_ + dh)*R_ + r]);
            ak = bfs(((const u16*)Wk_lsr)[(h*DH_ + dh)*R_ + r]);
        } else {
            aq = ((const float*)Wq_lsr)[(h*DH_ + dh)*R_ + r];
            ak = ((const float*)Wk_lsr)[(h*DH_ + dh)*R_ + r];
        }
        Aq[r * 72 + dh] = tob(aq);
        Ak[r * 72 + dh] = tob(ak);
    }
    #pragma unroll
    for (int p = 0; p < 8; ++p) {
        const int e  = tid + p * 256;      // 0..2047
        const int n  = e >> 4, ch = e & 15;
        if (isbf) {
            uint2 wq = *(const uint2*)((const u16*)Wqkv + (size_t)(d0+n)*(3*D_) + h*DH_ + ch*4);
            uint2 wk = *(const uint2*)((const u16*)Wqkv + (size_t)(d0+n)*(3*D_) + D_ + h*DH_ + ch*4);
            *(uint2*)&Bq[n * 72 + ch*4] = wq;
            *(uint2*)&Bk[n * 72 + ch*4] = wk;
        } else {
            float4 fq = *(const float4*)((const float*)Wqkv + (size_t)(d0+n)*(3*D_) + h*DH_ + ch*4);
            float4 fk = *(const float4*)((const float*)Wqkv + (size_t)(d0+n)*(3*D_) + D_ + h*DH_ + ch*4);
            uint2 oq, ok;
            oq.x = pack2(fq.x, fq.y); oq.y = pack2(fq.z, fq.w);
            ok.x = pack2(fk.x, fk.y); ok.y = pack2(fk.z, fk.w);
            *(uint2*)&Bq[n * 72 + ch*4] = oq;
            *(uint2*)&Bk[n * 72 + ch*4] = ok;
        }
    }
    __syncthreads();

    floatx4 accq[2][2], acck[2][2];
    #pragma unroll
    for (int mi = 0; mi < 2; ++mi)
        #pragma unroll
        for (int ni = 0; ni < 2; ++ni) { accq[mi][ni] = (floatx4)(0.f); acck[mi][ni] = (floatx4)(0.f); }

    #pragma unroll
    for (int kk = 0; kk < 2; ++kk) {
        bhalf8 aqf[2], akf[2], bqf[2], bkf[2];
        #pragma unroll
        for (int mi = 0; mi < 2; ++mi) {
            aqf[mi] = *(const bhalf8*)&Aq[(mi*16 + n16) * 72 + kk*32 + q4*8];
            akf[mi] = *(const bhalf8*)&Ak[(mi*16 + n16) * 72 + kk*32 + q4*8];
        }
        #pragma unroll
        for (int ni = 0; ni < 2; ++ni) {
            bqf[ni] = *(const bhalf8*)&Bq[(w*32 + ni*16 + n16) * 72 + kk*32 + q4*8];
            bkf[ni] = *(const bhalf8*)&Bk[(w*32 + ni*16 + n16) * 72 + kk*32 + q4*8];
        }
        #pragma unroll
        for (int mi = 0; mi < 2; ++mi)
            #pragma unroll
            for (int ni = 0; ni < 2; ++ni) {
                accq[mi][ni] = __builtin_amdgcn_mfma_f32_16x16x32_bf16(aqf[mi], bqf[ni], accq[mi][ni], 0, 0, 0);
                acck[mi][ni] = __builtin_amdgcn_mfma_f32_16x16x32_bf16(akf[mi], bkf[ni], acck[mi][ni], 0, 0, 0);
            }
    }

    const float scale = (float)(0.17677669529663687 * 1.4426950408889634);
    #pragma unroll
    for (int mi = 0; mi < 2; ++mi) {
        #pragma unroll
        for (int rr = 0; rr < 4; ++rr) {
            const int r = mi*16 + q4*4 + rr;
            const float cc = (isbf ? bfs(((const u16*)core)[h*R_ + r])
                                   : ((const float*)core)[h*R_ + r]) * scale;
            #pragma unroll
            for (int ni = 0; ni < 2; ++ni) {
                const int d = d0 + w*32 + ni*16 + n16;
                WcatT[(size_t)(h*R_ + r) * D_ + d]       = tob(accq[mi][ni][rr] * cc);
                WcatT[(size_t)(512 + h*R_ + r) * D_ + d] = tob(acck[mi][ni][rr]);
            }
        }
    }
}

// ---------------------------------------------------------------------------
// Kernel 1 (R19): MFMA gemm1  xb(4096,1024) @ WcatT^T -> ql + kfrag + vfrag.
// 128x64 tile, BK=64, gload16 staging, 1024 blocks, T1 XCD-chunked swizzle
// (each XCD: 4 contiguous bm-panels x all bn -> B 4MB + A 1MB ~= L2).
// kfrag: [bh][tile][(t&127)*32 + (r ^ ((t&3)<<3))] — bank-XOR pre-applied.
// vfrag: [bh][tile][kc][c2][lane][j] — sigma pre-applied (R17).
// ---------------------------------------------------------------------------
__global__ __launch_bounds__(256, 4) void gemm1_mfma(
    const u16* __restrict__ xb, const u16* __restrict__ WcatT,
    u16* __restrict__ ql, u16* __restrict__ kf, u16* __restrict__ vf)
{
    __shared__ __align__(16) u16 As[128 * 64];   // 16384 B, linear
    __shared__ __align__(16) u16 Bs[64 * 64];    //  8192 B, linear
    const int tid  = threadIdx.x;
    const int lane = tid & 63;
    const int w    = tid >> 6;
    const int n16  = lane & 15;
    const int q4   = lane >> 4;
    const int wx   = w & 1;          // n-half (32 cols)
    const int wy   = w >> 1;         // m-half (64 rows)
    const int bid  = blockIdx.x;
    const int lid  = (bid & 7) * 128 + (bid >> 3);   // T1 XCD chunking
    const int bm   = (lid >> 5) * 128;
    const int bn   = (lid & 31) * 64;
    const int lrow = lane >> 3;          // 0..7: row within 8-row stripe
    const int lcol = (lane & 7) * 8;     // u16 col within 64-col row

    floatx4 acc[4][2];
    #pragma unroll
    for (int i = 0; i < 4; ++i)
        #pragma unroll
        for (int j = 0; j < 2; ++j) acc[i][j] = (floatx4)(0.f);

    for (int kt = 0; kt < D_; kt += 64) {
        #pragma unroll
        for (int i = 0; i < 4; ++i) {
            const int r0 = w*32 + i*8;
            gload16(xb + (size_t)(bm + r0 + lrow) * D_ + kt + lcol, &As[r0 * 64]);
        }
        #pragma unroll
        for (int i = 0; i < 2; ++i) {
            const int r0 = w*16 + i*8;
            gload16(WcatT + (size_t)(bn + r0 + lrow) * D_ + kt + lcol, &Bs[r0 * 64]);
        }
        __syncthreads();
        #pragma unroll
        for (int kk = 0; kk < 2; ++kk) {
            bhalf8 a[4], b[2];
            #pragma unroll
            for (int mi = 0; mi < 4; ++mi)
                a[mi] = *(const bhalf8*)&As[(wy*64 + mi*16 + n16) * 64 + kk*32 + q4*8];
            #pragma unroll
            for (int ni = 0; ni < 2; ++ni)
                b[ni] = *(const bhalf8*)&Bs[(wx*32 + ni*16 + n16) * 64 + kk*32 + q4*8];
            #pragma unroll
            for (int mi = 0; mi < 4; ++mi)
                #pragma unroll
                for (int ni = 0; ni < 2; ++ni)
                    acc[mi][ni] = __builtin_amdgcn_mfma_f32_16x16x32_bf16(
                        a[mi], b[ni], acc[mi][ni], 0, 0, 0);
        }
        __syncthreads();
    }

    if (bn < 1024) {
        #pragma unroll
        for (int mi = 0; mi < 4; ++mi) {
            #pragma unroll
            for (int rr = 0; rr < 4; ++rr) {
                const int row = bm + wy*64 + mi*16 + q4*4 + rr;
                const int b   = row >> 11;
                const int t   = row & (T_ - 1);
                #pragma unroll
                for (int ni = 0; ni < 2; ++ni) {
                    const int col = bn + wx*32 + ni*16 + n16;
                    const u16 val = tob(acc[mi][ni][rr]);
                    if (col < 512) {
                        const int h = col >> 5, r = col & 31;
                        ql[((size_t)(b*H_ + h)*T_ + t)*R_ + r] = val;
                    } else {
                        const int c = col - 512; const int h = c >> 5, r = c & 31;
                        const int bh = b*H_ + h;
                        // kfrag: bank-XOR pre-applied (t&3 == rr here)
                        kf[((size_t)bh*16 + (t >> 7)) * 4096
                           + (size_t)(t & 127) * 32 + (r ^ (rr << 3))] = val;
                    }
                }
            }
        }
    } else {
        // v -> vfrag (attn fragment order). Thread owns V[t..t+3][dh].
        #pragma unroll
        for (int mi = 0; mi < 4; ++mi) {
            const int row0 = bm + wy*64 + mi*16 + q4*4;   // multiple of 4
            const int b  = row0 >> 11;
            const int t  = row0 & (T_ - 1);
            const int tile = t >> 7;
            const int sl   = t & 127;                     // sl % 4 == 0
            const int kc   = sl >> 5;
            const int j2   = (sl >> 4) & 1;
            const int qv   = (sl >> 2) & 3;
            #pragma unroll
            for (int ni = 0; ni < 2; ++ni) {
                const int c  = bn - 1024 + wx*32 + ni*16 + n16;  // 0..1023
                const int h  = c >> 6, dh = c & 63;
                const int bh = b*H_ + h;
                const int c2 = dh >> 4;
                const int lv = qv*16 + (dh & 15);
                u16* dst = vf + ((((size_t)bh*16 + tile)*4 + kc)*4 + c2)*512
                              + lv*8 + j2*4;
                uint2 o;
                o.x = pack2(acc[mi][ni][0], acc[mi][ni][1]);
                o.y = pack2(acc[mi][ni][2], acc[mi][ni][3]);
                *(uint2*)dst = o;
            }
        }
    }
}

// ---------------------------------------------------------------------------
// softmax update, one q-row per lane; alpha/l fully lane-local (R18 O^T PV).
// ---------------------------------------------------------------------------
__device__ __forceinline__ void softmax_update(
    floatx4 (&Sc)[8], float &mrow, float &lrow, floatx4 (&O)[4])
{
    float cmax[8];
    #pragma unroll
    for (int c = 0; c < 8; ++c)
        cmax[c] = fmaxf(fmaxf(Sc[c][0], Sc[c][1]), fmaxf(Sc[c][2], Sc[c][3]));
    float rmax = fmaxf(fmaxf(fmaxf(cmax[0], cmax[1]), fmaxf(cmax[2], cmax[3])),
                       fmaxf(fmaxf(cmax[4], cmax[5]), fmaxf(cmax[6], cmax[7])));
    rmax = fmaxf(rmax, __shfl_xor(rmax, 16, 64));
    rmax = fmaxf(rmax, __shfl_xor(rmax, 32, 64));

    const float mn = fmaxf(mrow, rmax);
    const int norescale = __all(rmax <= mrow);     // exact: alpha == 1

    float csum[8];
    #pragma unroll
    for (int c = 0; c < 8; ++c) {
        #pragma unroll
        for (int r = 0; r < 4; ++r)
            Sc[c][r] = __builtin_amdgcn_exp2f(Sc[c][r] - mn);
        csum[c] = (Sc[c][0] + Sc[c][1]) + (Sc[c][2] + Sc[c][3]);
    }
    float rsum = ((csum[0] + csum[1]) + (csum[2] + csum[3]))
               + ((csum[4] + csum[5]) + (csum[6] + csum[7]));
    rsum += __shfl_xor(rsum, 16, 64);
    rsum += __shfl_xor(rsum, 32, 64);

    if (norescale) {
        lrow += rsum;                              // mn == mrow exactly
    } else {
        const float alpha = __builtin_amdgcn_exp2f(mrow - mn);
        mrow = mn;
        lrow = lrow * alpha + rsum;
        #pragma unroll
        for (int c2 = 0; c2 < 4; ++c2)
            #pragma unroll
            for (int r = 0; r < 4; ++r) O[c2][r] *= alpha;
    }
}

// ---------------------------------------------------------------------------
// Kernel 2 (R19): swapped-QK flash attention, 512-thr, 128-row q-tiles,
// complementary pairing. ALL staging is async gload16 into double-buffered
// linear LDS (K from kfrag with bank-XOR read; V from vfrag, lane-linear).
// ONE barrier per s-tile: its vmcnt drain = data-ready for buf[cur]; next
// tile's gloads (into buf[cur^1]) issue right after it, hiding under
// compute (R18 pipeline). PV = O^T mfma -> lane-local alpha/l/epilogue.
// ---------------------------------------------------------------------------
__global__ __launch_bounds__(512, 4) void attn_kernel(
    const u16* __restrict__ ql, const u16* __restrict__ kf,
    const u16* __restrict__ vf, u16* __restrict__ y)
{
    __shared__ __align__(16) u16 kls[2][4096];       // 16384 B, linear dbuf
    __shared__ __align__(16) u16 vsT[2][8192];       // 32768 B, linear dbuf

    const int tid  = threadIdx.x;
    const int lane = tid & 63;
    const int w    = tid >> 6;               // 0..7
    const int n16  = lane & 15;
    const int q4   = lane >> 4;
    const int bh   = blockIdx.x;
    const int by   = blockIdx.y;             // 0..15
    const int qt2  = (by < 8) ? (15 - by) : (by - 8);  // complementary pairs
    const int t0   = qt2 * 128;
    const int nt   = qt2 + 1;                // # of 128-wide s-tiles

    // Q fragment = B-operand of swapped QK^T; loads directly in frag layout.
    const u16* qlb = ql + (size_t)bh * T_ * R_;
    const bhalf8 aq = *(const bhalf8*)(qlb + (size_t)(t0 + w*16 + n16) * R_ + q4*8);

    const u16* kfb = kf + (size_t)bh * 65536;    // 16 tiles * 4096 u16
    const u16* vfb = vf + (size_t)bh * 131072;   // 16 tiles * 8192 u16

    // prologue: tile 0 -> buf 0 (1 K gload + 2 V gloads per wave)
    gload16(kfb + (size_t)w * 512 + lane*8,        &kls[0][w * 512]);
    gload16(vfb + (size_t)(w*2    ) * 512 + lane*8, &vsT[0][(w*2    ) * 512]);
    gload16(vfb + (size_t)(w*2 + 1) * 512 + lane*8, &vsT[0][(w*2 + 1) * 512]);

    // K fragment read base: row = 16c+n16, XOR col = (q4 ^ (n16&3))*8.
    const int kbase = n16*32 + ((q4 ^ (n16 & 3)) * 8);

    float mrow = NEG_, lrow = 0.f;           // one q-row per lane
    floatx4 O[4];
    #pragma unroll
    for (int c = 0; c < 4; ++c) O[c] = (floatx4)(0.f);

    for (int it = 0; it < nt; ++it) {
        const int cur = it & 1;
        __syncthreads();   // drains buf[cur] gloads (data ready) AND proves
                           // all waves finished reading buf[cur^1]
        if (it + 1 < nt) {
            const u16* kn = kfb + (size_t)(it + 1) * 4096;
            const u16* vn = vfb + (size_t)(it + 1) * 8192;
            gload16(kn + (size_t)w * 512 + lane*8,        &kls[cur ^ 1][w * 512]);
            gload16(vn + (size_t)(w*2    ) * 512 + lane*8, &vsT[cur ^ 1][(w*2    ) * 512]);
            gload16(vn + (size_t)(w*2 + 1) * 512 + lane*8, &vsT[cur ^ 1][(w*2 + 1) * 512]);
        }

        // S^T: A = K-frag (m=s), B = Q-frag (n=q). Lane: q=n16, s=16c+4q4+r.
        floatx4 Sc[8];
        const u16* kb = &kls[cur][kbase];
        #pragma unroll
        for (int c = 0; c < 8; ++c) {
            bhalf8 ak = *(const bhalf8*)(kb + c * 512);
            Sc[c] = __builtin_amdgcn_mfma_f32_16x16x32_bf16(ak, aq, (floatx4)(0.f), 0, 0, 0);
        }

        if (it == nt - 1) {
            const int tq = w*16 + n16;                 // local q row (0..127)
            #pragma unroll
            for (int c = 0; c < 8; ++c) {
                const int sb = 16*c + 4*q4;            // local s base (s0==t0)
                #pragma unroll
                for (int r = 0; r < 4; ++r)
                    if (sb + r > tq) Sc[c][r] = NEG_;
            }
        }

        softmax_update(Sc, mrow, lrow, O);

        // PV (O^T): A = V-frag from vsT (lane-linear b128), B = P-frag
        // packed from lane's own Sc (sigma order, R13). O cols = q = n16.
        const u16* vt = &vsT[cur][lane * 8];
        #pragma unroll
        for (int kc = 0; kc < 4; ++kc) {
            union { u32 wd[4]; bhalf8 v; } pu;
            pu.wd[0] = pack2(Sc[2*kc    ][0], Sc[2*kc    ][1]);
            pu.wd[1] = pack2(Sc[2*kc    ][2], Sc[2*kc    ][3]);
            pu.wd[2] = pack2(Sc[2*kc + 1][0], Sc[2*kc + 1][1]);
            pu.wd[3] = pack2(Sc[2*kc + 1][2], Sc[2*kc + 1][3]);
            const bhalf8 pa = pu.v;
            #pragma unroll
            for (int c2 = 0; c2 < 4; ++c2) {
                bhalf8 bv = *(const bhalf8*)(vt + (size_t)(kc*4 + c2) * 512);
                O[c2] = __builtin_amdgcn_mfma_f32_16x16x32_bf16(bv, pa, O[c2], 0, 0, 0);
            }
        }
    }

    // Epilogue: fully lane-local. Lane holds O^T[dh = 16c2+4q4+rr][q = n16].
    const int b = bh >> 4, h = bh & 15;
    const float rl = 1.0f / lrow;
    const int t = t0 + w*16 + n16;
    u16* yr = y + ((size_t)b * T_ + t) * D_ + h * DH_;
    #pragma unroll
    for (int c2 = 0; c2 < 4; ++c2) {
        uint2 o;
        o.x = pack2(O[c2][0] * rl, O[c2][1] * rl);
        o.y = pack2(O[c2][2] * rl, O[c2][3] * rl);
        *(uint2*)(yr + 16*c2 + 4*q4) = o;
    }
}

// ---------------------------------------------------------------------------
// Kernel 3 (R19): MFMA out-gemm  yb(4096,1024) @ WoT^T -> out fp32.
// 64x64 tile, gload16 staging, 1024 blocks, T1 XCD-chunked swizzle
// (each XCD: 8 bm-panels x all bn -> B 2MB + A 1MB in its L2).
// ---------------------------------------------------------------------------
__global__ __launch_bounds__(256, 4) void out_gemm_mfma(
    const u16* __restrict__ yb, const u16* __restrict__ WoT,
    float* __restrict__ out)
{
    __shared__ __align__(16) u16 As[64 * 64];   // 8192 B, linear
    __shared__ __align__(16) u16 Bs[64 * 64];   // 8192 B, linear
    const int tid  = threadIdx.x;
    const int lane = tid & 63;
    const int w    = tid >> 6;
    const int n16  = lane & 15;
    const int q4   = lane >> 4;
    const int wx   = w & 1;          // n-half (32 cols)
    const int wy   = w >> 1;         // m-half (32 rows)
    const int bid  = blockIdx.x;
    const int lid  = (bid & 7) * 128 + (bid >> 3);   // T1 XCD chunking
    const int bm   = (lid >> 4) * 64;
    const int bn   = (lid & 15) * 64;
    const int lrow = lane >> 3;
    const int lcol = (lane & 7) * 8;

    floatx4 acc[2][2];
    #pragma unroll
    for (int i = 0; i < 2; ++i)
        #pragma unroll
        for (int j = 0; j < 2; ++j) acc[i][j] = (floatx4)(0.f);

    for (int kt = 0; kt < D_; kt += 64) {
        #pragma unroll
        for (int i = 0; i < 2; ++i) {
            const int r0 = w*16 + i*8;
            gload16(yb  + (size_t)(bm + r0 + lrow) * D_ + kt + lcol, &As[r0 * 64]);
            gload16(WoT + (size_t)(bn + r0 + lrow) * D_ + kt + lcol, &Bs[r0 * 64]);
        }
        __syncthreads();
        #pragma unroll
        for (int kk = 0; kk < 2; ++kk) {
            bhalf8 a[2], b[2];
            #pragma unroll
            for (int mi = 0; mi < 2; ++mi)
                a[mi] = *(const bhalf8*)&As[(wy*32 + mi*16 + n16) * 64 + kk*32 + q4*8];
            #pragma unroll
            for (int ni = 0; ni < 2; ++ni)
                b[ni] = *(const bhalf8*)&Bs[(wx*32 + ni*16 + n16) * 64 + kk*32 + q4*8];
            #pragma unroll
            for (int mi = 0; mi < 2; ++mi)
                #pragma unroll
                for (int ni = 0; ni < 2; ++ni)
                    acc[mi][ni] = __builtin_amdgcn_mfma_f32_16x16x32_bf16(
                        a[mi], b[ni], acc[mi][ni], 0, 0, 0);
        }
        __syncthreads();
    }

    #pragma unroll
    for (int mi = 0; mi < 2; ++mi) {
        #pragma unroll
        for (int rr = 0; rr < 4; ++rr) {
            const int row = bm + wy*32 + mi*16 + q4*4 + rr;
            #pragma unroll
            for (int ni = 0; ni < 2; ++ni) {
                const int col = bn + wx*32 + ni*16 + n16;
                out[(size_t)row * D_ + col] = acc[mi][ni][rr];
            }
        }
    }
}

// ---------------------------------------------------------------------------
extern "C" void kernel_launch(void* const* d_in, const int* in_sizes, int n_in,
                              void* d_out, int out_size, void* d_ws, size_t ws_size,
                              hipStream_t stream)
{
    (void)out_size; (void)ws_size;
    const void* in_x = nullptr; const void* in_wqkv = nullptr;
    const void* in_wq = nullptr; const void* in_wk = nullptr;
    const void* in_core = nullptr; const void* in_wo = nullptr;
    for (int i = 0; i < n_in; ++i) {
        const int s = in_sizes[i];
        if      (s == BT_*D_)     { if (!in_x)    in_x    = d_in[i]; }
        else if (s == D_*3*D_)    { if (!in_wqkv) in_wqkv = d_in[i]; }
        else if (s == H_*DH_*R_)  { if (!in_wq)   in_wq   = d_in[i]; else if (!in_wk) in_wk = d_in[i]; }
        else if (s == H_*R_)      { if (!in_core) in_core = d_in[i]; }
        else if (s == D_*D_)      { if (!in_wo)   in_wo   = d_in[i]; }
    }
    if (!in_x)    in_x    = d_in[0];
    if (!in_wqkv) in_wqkv = d_in[1];
    if (!in_wq)   in_wq   = d_in[2];
    if (!in_wk)   in_wk   = d_in[3];
    if (!in_core) in_core = d_in[4];
    if (!in_wo)   in_wo   = d_in[5];

    float* out = (float*)d_out;

    char* ws    = (char*)d_ws;
    u16*  xb    = (u16*)(ws + WSB_XB);
    u16*  WcatT = (u16*)(ws + WSB_WCATT);
    u16*  ql    = (u16*)(ws + WSB_QL);
    u16*  kf    = (u16*)(ws + WSB_KF);
    u16*  vf    = (u16*)(ws + WSB_VT);
    u16*  yb    = (u16*)(ws + WSB_YB);
    u16*  WoT   = (u16*)(ws + WSB_WOT);

    prep_kernel<<<2688, 256, 0, stream>>>(in_x, xb, in_wqkv, in_wo,
                                          in_wq, in_wk, in_core, WcatT, WoT);
    gemm1_mfma<<<1024, 256, 0, stream>>>(xb, WcatT, ql, kf, vf);
    attn_kernel<<<dim3(32, 16), 512, 0, stream>>>(ql, kf, vf, yb);
    out_gemm_mfma<<<1024, 256, 0, stream>>>(yb, WoT, out);
}

// Round 9
// 179.205 us; speedup vs baseline: 1.0059x; 1.0059x over previous
//
#include <hip/hip_runtime.h>
#include <hip/hip_bf16.h>

// Rounds 0-19: fp32 inputs (inline detector), fp32 out, bf16 MFMA.
// R10: loads just before __syncthreads are DEFEATED (vmcnt(0) drain) unless
// issued a full compute-phase earlier (R18). R12: swapped-QK attn, lane-
// local softmax, exp2-domain, rescale-skip. R13: zero-LDS P path (sigma).
// R14: 512-thr attn, shared staging, complementary pairing. R17: falsified
// barrier-theory; kept vfrag (V pre-laid in frag order -> linear staging).
// R18: vfrag gload16 dbuf + O^T PV (lane-local alpha/l/epilogue) = 176.7
// BEST. R19: kfrag(bad XOR key t&3 -> still 4-way) + T1 swizzle (forced
// full 4MB B into every XCD L2) bundled = 180.3 regression, unattributable.
// R20 (this round): R18 exactly + ONLY the attn kfrag/single-barrier
// change, XOR key corrected to (t>>1)&3 -> 2 lanes/bank-slot = free (m136):
//  - gemm1 K-epilogue writes kfrag [bh][tile][(t&127)*32 + (r^key)]
//  - attn: ALL staging async gload16, dbuf; ONE barrier per s-tile (drain
//    = data-ready; buf[cur^1] written only after barrier proving all waves
//    done reading it); K read at chunk q4 ^ ((n16>>1)&3).
// Pre-committed: total >= 176 -> R18 structure is the floor; present
// floor arithmetic next round.
#define B_  2
#define T_  2048
#define D_  1024
#define H_  16
#define DH_ 64
#define R_  32
#define BT_ (B_*T_)          // 4096
#define BH_ (B_*H_)          // 32

typedef unsigned short u16;
typedef unsigned int   u32;
typedef __attribute__((ext_vector_type(8))) short bhalf8;   // 8 bf16 = 4 VGPRs
typedef __attribute__((ext_vector_type(4))) float floatx4;  // MFMA C/D

// Workspace layout (bytes). Total ~38 MB.
#define WSB_FLAG  0
#define WSB_XB    256                        // bf16 x     (4096,1024)  8 MB
#define WSB_WCATT (WSB_XB    + 8388608)      // bf16 WcatT (2048,1024)  4 MB
#define WSB_QL    (WSB_WCATT + 4194304)      // bf16 (B,H,T,R)          4 MB
#define WSB_KF    (WSB_QL    + 4194304)      // bf16 kfrag (B,H,...)    4 MB
#define WSB_VT    (WSB_KF    + 4194304)      // bf16 vfrag (B,H,...)    8 MB
#define WSB_YB    (WSB_VT    + 8388608)      // bf16 y     (B,T,D)      8 MB
#define WSB_WOT   (WSB_YB    + 8388608)      // bf16 WoT   (1024,1024)  2 MB

#define NEG_ -1.0e30f

__device__ __forceinline__ float bfs(u16 s) {
    union { u32 i; float f; } w; w.i = ((u32)s) << 16; return w.f;
}
__device__ __forceinline__ u16 tob(float f) {
    __hip_bfloat16 h = __float2bfloat16(f);   // RNE
    return *(u16*)&h;
}
__device__ __forceinline__ u32 pack2(float a, float b) {
    return (u32)tob(a) | ((u32)tob(b) << 16);
}
// Direct global->LDS staging, 16B/lane. LDS base wave-uniform; HW writes
// base + lane*16. Global address is per-lane.
__device__ __forceinline__ void gload16(const u16* g, u16* l) {
    __builtin_amdgcn_global_load_lds(
        (const __attribute__((address_space(1))) void*)g,
        (__attribute__((address_space(3))) void*)l, 16, 0, 0);
}
// Inline dtype detect (1 = bf16, 0 = fp32) from first 2KB of x.
__device__ __forceinline__ int detect_isbf(const u32* __restrict__ xw, int lane) {
    int hits = 0;
    #pragma unroll
    for (int i = 0; i < 8; ++i) {
        const u32 w = xw[lane + i * 64];
        const u32 h = w & 0xFFFFu;
        const u32 e = (h >> 7) & 0xFFu;
        if (h == 0u || (e >= 100u && e <= 150u)) ++hits;
    }
    #pragma unroll
    for (int off = 32; off; off >>= 1) hits += __shfl_down(hits, off, 64);
    return __shfl(hits, 0, 64) >= 300;
}

// ---------------------------------------------------------------------------
// Kernel P: fused preprocessing (R17, unchanged).
//  blocks 0..2047   : x -> xb bf16 (8 elems/thread)
//  blocks 2048..2303: transposing convert W_v slice of Wqkv -> WcatT[1024..]
//  blocks 2304..2559: transposing convert W_o -> WoT
//  blocks 2560..2687: fold via MFMA (scale incl 1/sqrt(32)*log2(e))
// ---------------------------------------------------------------------------
__global__ __launch_bounds__(256) void prep_kernel(
    const void* __restrict__ x, u16* __restrict__ xb,
    const void* __restrict__ Wqkv, const void* __restrict__ Wo,
    const void* __restrict__ Wq_lsr, const void* __restrict__ Wk_lsr,
    const void* __restrict__ core,
    u16* __restrict__ WcatT, u16* __restrict__ WoT)
{
    __shared__ __align__(16) u16 Bq[128 * 72];   // fold [n=d][k=dh]; also T-tile
    __shared__ __align__(16) u16 Bk[128 * 72];
    __shared__ __align__(16) u16 Aq[32 * 72];    // fold [m=r][k=dh]
    __shared__ __align__(16) u16 Ak[32 * 72];
    const int tid  = threadIdx.x;
    const int lane = tid & 63;
    const int isbf = detect_isbf((const u32*)x, lane);
    const int blk  = blockIdx.x;
    const int w    = tid >> 6;
    const int n16  = lane & 15;
    const int q4   = lane >> 4;

    if (blk < 2048) {
        const int e = blk * 256 + tid;           // over 524288 (x8 elems)
        if (isbf) {
            ((uint4*)xb)[e] = ((const uint4*)x)[e];
        } else {
            float4 a0 = ((const float4*)x)[2*e];
            float4 a1 = ((const float4*)x)[2*e + 1];
            uint4 o;
            o.x = pack2(a0.x, a0.y); o.y = pack2(a0.z, a0.w);
            o.z = pack2(a1.x, a1.y); o.w = pack2(a1.z, a1.w);
            ((uint4*)xb)[e] = o;
        }
        return;
    }

    if (blk < 2560) {
        // transposing convert, 64x64 tiles (uses Bq as scratch tile)
        int t = blk - 2048;
        const void* src; u16* dst; int srcStride, srcColOff, dstRowOff;
        if (t < 256) { src = Wqkv; dst = WcatT; srcStride = 3*D_; srcColOff = 2*D_; dstRowOff = 1024; }
        else { t -= 256; src = Wo; dst = WoT; srcStride = D_; srcColOff = 0; dstRowOff = 0; }
        const int j0 = (t & 15) * 64;
        const int i0 = (t >> 4) * 64;
        #pragma unroll
        for (int p = 0; p < 2; ++p) {
            const int e = tid + p * 256;
            const int r = e >> 3, ch = e & 7;
            if (isbf) {
                uint4 v = *(const uint4*)((const u16*)src + (size_t)(i0 + r) * srcStride + srcColOff + j0 + ch*8);
                *(uint4*)&Bq[r * 72 + ch*8] = v;
            } else {
                const float* s = (const float*)src + (size_t)(i0 + r) * srcStride + srcColOff + j0 + ch*8;
                float4 a0 = *(const float4*)s;
                float4 a1 = *(const float4*)(s + 4);
                uint4 o;
                o.x = pack2(a0.x, a0.y); o.y = pack2(a0.z, a0.w);
                o.z = pack2(a1.x, a1.y); o.w = pack2(a1.z, a1.w);
                *(uint4*)&Bq[r * 72 + ch*8] = o;
            }
        }
        __syncthreads();
        #pragma unroll
        for (int p = 0; p < 2; ++p) {
            const int e = tid + p * 256;
            const int c = e >> 3, ch = e & 7;
            u16 tmp[8];
            #pragma unroll
            for (int j = 0; j < 8; ++j) tmp[j] = Bq[(ch*8 + j) * 72 + c];
            *(uint4*)(dst + (size_t)(dstRowOff + j0 + c) * D_ + i0 + ch*8) = *(uint4*)tmp;
        }
        return;
    }

    // fold: per head h, Cq(32x1024) = Aq_h^T(32x64) @ Wq_h(64x1024)
    const int fb = blk - 2560;          // 0..127
    const int h  = fb & 15;
    const int d0 = (fb >> 4) * 128;

    #pragma unroll
    for (int p = 0; p < 8; ++p) {
        const int e  = tid + p * 256;
        const int r  = e & 31, dh = e >> 5;
        float aq, ak;
        if (isbf) {
            aq = bfs(((const u16*)Wq_lsr)[(h*DH_ + dh)*R_ + r]);
            ak = bfs(((const u16*)Wk_lsr)[(h*DH_ + dh)*R_ + r]);
        } else {
            aq = ((const float*)Wq_lsr)[(h*DH_ + dh)*R_ + r];
            ak = ((const float*)Wk_lsr)[(h*DH_ + dh)*R_ + r];
        }
        Aq[r * 72 + dh] = tob(aq);
        Ak[r * 72 + dh] = tob(ak);
    }
    #pragma unroll
    for (int p = 0; p < 8; ++p) {
        const int e  = tid + p * 256;      // 0..2047
        const int n  = e >> 4, ch = e & 15;
        if (isbf) {
            uint2 wq = *(const uint2*)((const u16*)Wqkv + (size_t)(d0+n)*(3*D_) + h*DH_ + ch*4);
            uint2 wk = *(const uint2*)((const u16*)Wqkv + (size_t)(d0+n)*(3*D_) + D_ + h*DH_ + ch*4);
            *(uint2*)&Bq[n * 72 + ch*4] = wq;
            *(uint2*)&Bk[n * 72 + ch*4] = wk;
        } else {
            float4 fq = *(const float4*)((const float*)Wqkv + (size_t)(d0+n)*(3*D_) + h*DH_ + ch*4);
            float4 fk = *(const float4*)((const float*)Wqkv + (size_t)(d0+n)*(3*D_) + D_ + h*DH_ + ch*4);
            uint2 oq, ok;
            oq.x = pack2(fq.x, fq.y); oq.y = pack2(fq.z, fq.w);
            ok.x = pack2(fk.x, fk.y); ok.y = pack2(fk.z, fk.w);
            *(uint2*)&Bq[n * 72 + ch*4] = oq;
            *(uint2*)&Bk[n * 72 + ch*4] = ok;
        }
    }
    __syncthreads();

    floatx4 accq[2][2], acck[2][2];
    #pragma unroll
    for (int mi = 0; mi < 2; ++mi)
        #pragma unroll
        for (int ni = 0; ni < 2; ++ni) { accq[mi][ni] = (floatx4)(0.f); acck[mi][ni] = (floatx4)(0.f); }

    #pragma unroll
    for (int kk = 0; kk < 2; ++kk) {
        bhalf8 aqf[2], akf[2], bqf[2], bkf[2];
        #pragma unroll
        for (int mi = 0; mi < 2; ++mi) {
            aqf[mi] = *(const bhalf8*)&Aq[(mi*16 + n16) * 72 + kk*32 + q4*8];
            akf[mi] = *(const bhalf8*)&Ak[(mi*16 + n16) * 72 + kk*32 + q4*8];
        }
        #pragma unroll
        for (int ni = 0; ni < 2; ++ni) {
            bqf[ni] = *(const bhalf8*)&Bq[(w*32 + ni*16 + n16) * 72 + kk*32 + q4*8];
            bkf[ni] = *(const bhalf8*)&Bk[(w*32 + ni*16 + n16) * 72 + kk*32 + q4*8];
        }
        #pragma unroll
        for (int mi = 0; mi < 2; ++mi)
            #pragma unroll
            for (int ni = 0; ni < 2; ++ni) {
                accq[mi][ni] = __builtin_amdgcn_mfma_f32_16x16x32_bf16(aqf[mi], bqf[ni], accq[mi][ni], 0, 0, 0);
                acck[mi][ni] = __builtin_amdgcn_mfma_f32_16x16x32_bf16(akf[mi], bkf[ni], acck[mi][ni], 0, 0, 0);
            }
    }

    const float scale = (float)(0.17677669529663687 * 1.4426950408889634);
    #pragma unroll
    for (int mi = 0; mi < 2; ++mi) {
        #pragma unroll
        for (int rr = 0; rr < 4; ++rr) {
            const int r = mi*16 + q4*4 + rr;
            const float cc = (isbf ? bfs(((const u16*)core)[h*R_ + r])
                                   : ((const float*)core)[h*R_ + r]) * scale;
            #pragma unroll
            for (int ni = 0; ni < 2; ++ni) {
                const int d = d0 + w*32 + ni*16 + n16;
                WcatT[(size_t)(h*R_ + r) * D_ + d]       = tob(accq[mi][ni][rr] * cc);
                WcatT[(size_t)(512 + h*R_ + r) * D_ + d] = tob(acck[mi][ni][rr]);
            }
        }
    }
}

// ---------------------------------------------------------------------------
// Kernel 1 (R20): MFMA gemm1  xb(4096,1024) @ WcatT^T -> ql + kfrag + vfrag.
// R18 structure exactly (128x64 tile, gload16, 2D grid 32x32 = 1024 blocks,
// 4/CU); K-epilogue writes kfrag with CORRECTED bank-XOR key (t>>1)&3.
// kfrag: [bh][tile][(t&127)*32 + (r ^ (((t>>1)&3)<<3))].
// vfrag: [bh][tile][kc][c2][lane][j] — sigma pre-applied (R17).
// ---------------------------------------------------------------------------
__global__ __launch_bounds__(256, 4) void gemm1_mfma(
    const u16* __restrict__ xb, const u16* __restrict__ WcatT,
    u16* __restrict__ ql, u16* __restrict__ kf, u16* __restrict__ vf)
{
    __shared__ __align__(16) u16 As[128 * 64];   // 16384 B, linear
    __shared__ __align__(16) u16 Bs[64 * 64];    //  8192 B, linear
    const int tid  = threadIdx.x;
    const int lane = tid & 63;
    const int w    = tid >> 6;
    const int n16  = lane & 15;
    const int q4   = lane >> 4;
    const int wx   = w & 1;          // n-half (32 cols)
    const int wy   = w >> 1;         // m-half (64 rows)
    const int bm   = blockIdx.y * 128;
    const int bn   = blockIdx.x * 64;
    const int lrow = lane >> 3;          // 0..7: row within 8-row stripe
    const int lcol = (lane & 7) * 8;     // u16 col within 64-col row

    floatx4 acc[4][2];
    #pragma unroll
    for (int i = 0; i < 4; ++i)
        #pragma unroll
        for (int j = 0; j < 2; ++j) acc[i][j] = (floatx4)(0.f);

    for (int kt = 0; kt < D_; kt += 64) {
        #pragma unroll
        for (int i = 0; i < 4; ++i) {
            const int r0 = w*32 + i*8;
            gload16(xb + (size_t)(bm + r0 + lrow) * D_ + kt + lcol, &As[r0 * 64]);
        }
        #pragma unroll
        for (int i = 0; i < 2; ++i) {
            const int r0 = w*16 + i*8;
            gload16(WcatT + (size_t)(bn + r0 + lrow) * D_ + kt + lcol, &Bs[r0 * 64]);
        }
        __syncthreads();
        #pragma unroll
        for (int kk = 0; kk < 2; ++kk) {
            bhalf8 a[4], b[2];
            #pragma unroll
            for (int mi = 0; mi < 4; ++mi)
                a[mi] = *(const bhalf8*)&As[(wy*64 + mi*16 + n16) * 64 + kk*32 + q4*8];
            #pragma unroll
            for (int ni = 0; ni < 2; ++ni)
                b[ni] = *(const bhalf8*)&Bs[(wx*32 + ni*16 + n16) * 64 + kk*32 + q4*8];
            #pragma unroll
            for (int mi = 0; mi < 4; ++mi)
                #pragma unroll
                for (int ni = 0; ni < 2; ++ni)
                    acc[mi][ni] = __builtin_amdgcn_mfma_f32_16x16x32_bf16(
                        a[mi], b[ni], acc[mi][ni], 0, 0, 0);
        }
        __syncthreads();
    }

    if (bn < 1024) {
        #pragma unroll
        for (int mi = 0; mi < 4; ++mi) {
            #pragma unroll
            for (int rr = 0; rr < 4; ++rr) {
                const int row = bm + wy*64 + mi*16 + q4*4 + rr;
                const int b   = row >> 11;
                const int t   = row & (T_ - 1);
                #pragma unroll
                for (int ni = 0; ni < 2; ++ni) {
                    const int col = bn + wx*32 + ni*16 + n16;
                    const u16 val = tob(acc[mi][ni][rr]);
                    if (col < 512) {
                        const int h = col >> 5, r = col & 31;
                        ql[((size_t)(b*H_ + h)*T_ + t)*R_ + r] = val;
                    } else {
                        const int c = col - 512; const int h = c >> 5, r = c & 31;
                        const int bh = b*H_ + h;
                        const int key = ((t >> 1) & 3) << 3;   // 2-way-free XOR
                        kf[((size_t)bh*16 + (t >> 7)) * 4096
                           + (size_t)(t & 127) * 32 + (r ^ key)] = val;
                    }
                }
            }
        }
    } else {
        // v -> vfrag (attn fragment order). Thread owns V[t..t+3][dh].
        #pragma unroll
        for (int mi = 0; mi < 4; ++mi) {
            const int row0 = bm + wy*64 + mi*16 + q4*4;   // multiple of 4
            const int b  = row0 >> 11;
            const int t  = row0 & (T_ - 1);
            const int tile = t >> 7;
            const int sl   = t & 127;                     // sl % 4 == 0
            const int kc   = sl >> 5;
            const int j2   = (sl >> 4) & 1;
            const int qv   = (sl >> 2) & 3;
            #pragma unroll
            for (int ni = 0; ni < 2; ++ni) {
                const int c  = bn - 1024 + wx*32 + ni*16 + n16;  // 0..1023
                const int h  = c >> 6, dh = c & 63;
                const int bh = b*H_ + h;
                const int c2 = dh >> 4;
                const int lv = qv*16 + (dh & 15);
                u16* dst = vf + ((((size_t)bh*16 + tile)*4 + kc)*4 + c2)*512
                              + lv*8 + j2*4;
                uint2 o;
                o.x = pack2(acc[mi][ni][0], acc[mi][ni][1]);
                o.y = pack2(acc[mi][ni][2], acc[mi][ni][3]);
                *(uint2*)dst = o;
            }
        }
    }
}

// ---------------------------------------------------------------------------
// softmax update, one q-row per lane; alpha/l fully lane-local (R18 O^T PV).
// ---------------------------------------------------------------------------
__device__ __forceinline__ void softmax_update(
    floatx4 (&Sc)[8], float &mrow, float &lrow, floatx4 (&O)[4])
{
    float cmax[8];
    #pragma unroll
    for (int c = 0; c < 8; ++c)
        cmax[c] = fmaxf(fmaxf(Sc[c][0], Sc[c][1]), fmaxf(Sc[c][2], Sc[c][3]));
    float rmax = fmaxf(fmaxf(fmaxf(cmax[0], cmax[1]), fmaxf(cmax[2], cmax[3])),
                       fmaxf(fmaxf(cmax[4], cmax[5]), fmaxf(cmax[6], cmax[7])));
    rmax = fmaxf(rmax, __shfl_xor(rmax, 16, 64));
    rmax = fmaxf(rmax, __shfl_xor(rmax, 32, 64));

    const float mn = fmaxf(mrow, rmax);
    const int norescale = __all(rmax <= mrow);     // exact: alpha == 1

    float csum[8];
    #pragma unroll
    for (int c = 0; c < 8; ++c) {
        #pragma unroll
        for (int r = 0; r < 4; ++r)
            Sc[c][r] = __builtin_amdgcn_exp2f(Sc[c][r] - mn);
        csum[c] = (Sc[c][0] + Sc[c][1]) + (Sc[c][2] + Sc[c][3]);
    }
    float rsum = ((csum[0] + csum[1]) + (csum[2] + csum[3]))
               + ((csum[4] + csum[5]) + (csum[6] + csum[7]));
    rsum += __shfl_xor(rsum, 16, 64);
    rsum += __shfl_xor(rsum, 32, 64);

    if (norescale) {
        lrow += rsum;                              // mn == mrow exactly
    } else {
        const float alpha = __builtin_amdgcn_exp2f(mrow - mn);
        mrow = mn;
        lrow = lrow * alpha + rsum;
        #pragma unroll
        for (int c2 = 0; c2 < 4; ++c2)
            #pragma unroll
            for (int r = 0; r < 4; ++r) O[c2][r] *= alpha;
    }
}

// ---------------------------------------------------------------------------
// Kernel 2 (R20): swapped-QK flash attention, 512-thr, 128-row q-tiles,
// complementary pairing. ALL staging async gload16 into double-buffered
// linear LDS: K from kfrag (read chunk q4 ^ ((n16>>1)&3) -> 2 lanes/slot,
// free), V from vfrag (lane-linear, free). ONE barrier per s-tile: its
// per-wave vmcnt drain = data-ready for buf[cur]; gloads into buf[cur^1]
// issue right after it (all waves provably done reading buf[cur^1]) and
// hide under this tile's compute (R18 pipeline). PV = O^T mfma.
// ---------------------------------------------------------------------------
__global__ __launch_bounds__(512, 4) void attn_kernel(
    const u16* __restrict__ ql, const u16* __restrict__ kf,
    const u16* __restrict__ vf, u16* __restrict__ y)
{
    __shared__ __align__(16) u16 kls[2][4096];       // 16384 B, linear dbuf
    __shared__ __align__(16) u16 vsT[2][8192];       // 32768 B, linear dbuf

    const int tid  = threadIdx.x;
    const int lane = tid & 63;
    const int w    = tid >> 6;               // 0..7
    const int n16  = lane & 15;
    const int q4   = lane >> 4;
    const int bh   = blockIdx.x;
    const int by   = blockIdx.y;             // 0..15
    const int qt2  = (by < 8) ? (15 - by) : (by - 8);  // complementary pairs
    const int t0   = qt2 * 128;
    const int nt   = qt2 + 1;                // # of 128-wide s-tiles

    // Q fragment = B-operand of swapped QK^T; loads directly in frag layout.
    const u16* qlb = ql + (size_t)bh * T_ * R_;
    const bhalf8 aq = *(const bhalf8*)(qlb + (size_t)(t0 + w*16 + n16) * R_ + q4*8);

    const u16* kfb = kf + (size_t)bh * 65536;    // 16 tiles * 4096 u16
    const u16* vfb = vf + (size_t)bh * 131072;   // 16 tiles * 8192 u16

    // prologue: tile 0 -> buf 0 (1 K gload + 2 V gloads per wave)
    gload16(kfb + (size_t)w * 512 + lane*8,         &kls[0][w * 512]);
    gload16(vfb + (size_t)(w*2    ) * 512 + lane*8, &vsT[0][(w*2    ) * 512]);
    gload16(vfb + (size_t)(w*2 + 1) * 512 + lane*8, &vsT[0][(w*2 + 1) * 512]);

    // K fragment read base: row = 16c+n16, chunk = q4 ^ ((n16>>1)&3).
    const int kbase = n16*32 + ((q4 ^ ((n16 >> 1) & 3)) * 8);

    float mrow = NEG_, lrow = 0.f;           // one q-row per lane
    floatx4 O[4];
    #pragma unroll
    for (int c = 0; c < 4; ++c) O[c] = (floatx4)(0.f);

    for (int it = 0; it < nt; ++it) {
        const int cur = it & 1;
        __syncthreads();   // drains buf[cur] gloads (data ready) AND proves
                           // all waves finished reading buf[cur^1]
        if (it + 1 < nt) {
            const u16* kn = kfb + (size_t)(it + 1) * 4096;
            const u16* vn = vfb + (size_t)(it + 1) * 8192;
            gload16(kn + (size_t)w * 512 + lane*8,         &kls[cur ^ 1][w * 512]);
            gload16(vn + (size_t)(w*2    ) * 512 + lane*8, &vsT[cur ^ 1][(w*2    ) * 512]);
            gload16(vn + (size_t)(w*2 + 1) * 512 + lane*8, &vsT[cur ^ 1][(w*2 + 1) * 512]);
        }

        // S^T: A = K-frag (m=s), B = Q-frag (n=q). Lane: q=n16, s=16c+4q4+r.
        floatx4 Sc[8];
        const u16* kb = &kls[cur][kbase];
        #pragma unroll
        for (int c = 0; c < 8; ++c) {
            bhalf8 ak = *(const bhalf8*)(kb + c * 512);
            Sc[c] = __builtin_amdgcn_mfma_f32_16x16x32_bf16(ak, aq, (floatx4)(0.f), 0, 0, 0);
        }

        if (it == nt - 1) {
            const int tq = w*16 + n16;                 // local q row (0..127)
            #pragma unroll
            for (int c = 0; c < 8; ++c) {
                const int sb = 16*c + 4*q4;            // local s base (s0==t0)
                #pragma unroll
                for (int r = 0; r < 4; ++r)
                    if (sb + r > tq) Sc[c][r] = NEG_;
            }
        }

        softmax_update(Sc, mrow, lrow, O);

        // PV (O^T): A = V-frag from vsT (lane-linear b128), B = P-frag
        // packed from lane's own Sc (sigma order, R13). O cols = q = n16.
        const u16* vt = &vsT[cur][lane * 8];
        #pragma unroll
        for (int kc = 0; kc < 4; ++kc) {
            union { u32 wd[4]; bhalf8 v; } pu;
            pu.wd[0] = pack2(Sc[2*kc    ][0], Sc[2*kc    ][1]);
            pu.wd[1] = pack2(Sc[2*kc    ][2], Sc[2*kc    ][3]);
            pu.wd[2] = pack2(Sc[2*kc + 1][0], Sc[2*kc + 1][1]);
            pu.wd[3] = pack2(Sc[2*kc + 1][2], Sc[2*kc + 1][3]);
            const bhalf8 pa = pu.v;
            #pragma unroll
            for (int c2 = 0; c2 < 4; ++c2) {
                bhalf8 bv = *(const bhalf8*)(vt + (size_t)(kc*4 + c2) * 512);
                O[c2] = __builtin_amdgcn_mfma_f32_16x16x32_bf16(bv, pa, O[c2], 0, 0, 0);
            }
        }
    }

    // Epilogue: fully lane-local. Lane holds O^T[dh = 16c2+4q4+rr][q = n16].
    const int b = bh >> 4, h = bh & 15;
    const float rl = 1.0f / lrow;
    const int t = t0 + w*16 + n16;
    u16* yr = y + ((size_t)b * T_ + t) * D_ + h * DH_;
    #pragma unroll
    for (int c2 = 0; c2 < 4; ++c2) {
        uint2 o;
        o.x = pack2(O[c2][0] * rl, O[c2][1] * rl);
        o.y = pack2(O[c2][2] * rl, O[c2][3] * rl);
        *(uint2*)(yr + 16*c2 + 4*q4) = o;
    }
}

// ---------------------------------------------------------------------------
// Kernel 3 (R16/R18): MFMA out-gemm  yb(4096,1024) @ WoT^T -> out fp32.
// 64x64 tile, gload16 staging. Grid (16,64) = 1024 blocks = 4/CU. No T1.
// ---------------------------------------------------------------------------
__global__ __launch_bounds__(256, 4) void out_gemm_mfma(
    const u16* __restrict__ yb, const u16* __restrict__ WoT,
    float* __restrict__ out)
{
    __shared__ __align__(16) u16 As[64 * 64];   // 8192 B, linear
    __shared__ __align__(16) u16 Bs[64 * 64];   // 8192 B, linear
    const int tid  = threadIdx.x;
    const int lane = tid & 63;
    const int w    = tid >> 6;
    const int n16  = lane & 15;
    const int q4   = lane >> 4;
    const int wx   = w & 1;          // n-half (32 cols)
    const int wy   = w >> 1;         // m-half (32 rows)
    const int bm   = blockIdx.y * 64;
    const int bn   = blockIdx.x * 64;
    const int lrow = lane >> 3;
    const int lcol = (lane & 7) * 8;

    floatx4 acc[2][2];
    #pragma unroll
    for (int i = 0; i < 2; ++i)
        #pragma unroll
        for (int j = 0; j < 2; ++j) acc[i][j] = (floatx4)(0.f);

    for (int kt = 0; kt < D_; kt += 64) {
        #pragma unroll
        for (int i = 0; i < 2; ++i) {
            const int r0 = w*16 + i*8;
            gload16(yb  + (size_t)(bm + r0 + lrow) * D_ + kt + lcol, &As[r0 * 64]);
            gload16(WoT + (size_t)(bn + r0 + lrow) * D_ + kt + lcol, &Bs[r0 * 64]);
        }
        __syncthreads();
        #pragma unroll
        for (int kk = 0; kk < 2; ++kk) {
            bhalf8 a[2], b[2];
            #pragma unroll
            for (int mi = 0; mi < 2; ++mi)
                a[mi] = *(const bhalf8*)&As[(wy*32 + mi*16 + n16) * 64 + kk*32 + q4*8];
            #pragma unroll
            for (int ni = 0; ni < 2; ++ni)
                b[ni] = *(const bhalf8*)&Bs[(wx*32 + ni*16 + n16) * 64 + kk*32 + q4*8];
            #pragma unroll
            for (int mi = 0; mi < 2; ++mi)
                #pragma unroll
                for (int ni = 0; ni < 2; ++ni)
                    acc[mi][ni] = __builtin_amdgcn_mfma_f32_16x16x32_bf16(
                        a[mi], b[ni], acc[mi][ni], 0, 0, 0);
        }
        __syncthreads();
    }

    #pragma unroll
    for (int mi = 0; mi < 2; ++mi) {
        #pragma unroll
        for (int rr = 0; rr < 4; ++rr) {
            const int row = bm + wy*32 + mi*16 + q4*4 + rr;
            #pragma unroll
            for (int ni = 0; ni < 2; ++ni) {
                const int col = bn + wx*32 + ni*16 + n16;
                out[(size_t)row * D_ + col] = acc[mi][ni][rr];
            }
        }
    }
}

// ---------------------------------------------------------------------------
extern "C" void kernel_launch(void* const* d_in, const int* in_sizes, int n_in,
                              void* d_out, int out_size, void* d_ws, size_t ws_size,
                              hipStream_t stream)
{
    (void)out_size; (void)ws_size;
    const void* in_x = nullptr; const void* in_wqkv = nullptr;
    const void* in_wq = nullptr; const void* in_wk = nullptr;
    const void* in_core = nullptr; const void* in_wo = nullptr;
    for (int i = 0; i < n_in; ++i) {
        const int s = in_sizes[i];
        if      (s == BT_*D_)     { if (!in_x)    in_x    = d_in[i]; }
        else if (s == D_*3*D_)    { if (!in_wqkv) in_wqkv = d_in[i]; }
        else if (s == H_*DH_*R_)  { if (!in_wq)   in_wq   = d_in[i]; else if (!in_wk) in_wk = d_in[i]; }
        else if (s == H_*R_)      { if (!in_core) in_core = d_in[i]; }
        else if (s == D_*D_)      { if (!in_wo)   in_wo   = d_in[i]; }
    }
    if (!in_x)    in_x    = d_in[0];
    if (!in_wqkv) in_wqkv = d_in[1];
    if (!in_wq)   in_wq   = d_in[2];
    if (!in_wk)   in_wk   = d_in[3];
    if (!in_core) in_core = d_in[4];
    if (!in_wo)   in_wo   = d_in[5];

    float* out = (float*)d_out;

    char* ws    = (char*)d_ws;
    u16*  xb    = (u16*)(ws + WSB_XB);
    u16*  WcatT = (u16*)(ws + WSB_WCATT);
    u16*  ql    = (u16*)(ws + WSB_QL);
    u16*  kf    = (u16*)(ws + WSB_KF);
    u16*  vf    = (u16*)(ws + WSB_VT);
    u16*  yb    = (u16*)(ws + WSB_YB);
    u16*  WoT   = (u16*)(ws + WSB_WOT);

    prep_kernel<<<2688, 256, 0, stream>>>(in_x, xb, in_wqkv, in_wo,
                                          in_wq, in_wk, in_core, WcatT, WoT);
    gemm1_mfma<<<dim3(32, 32), 256, 0, stream>>>(xb, WcatT, ql, kf, vf);
    attn_kernel<<<dim3(32, 16), 512, 0, stream>>>(ql, kf, vf, yb);
    out_gemm_mfma<<<dim3(16, 64), 256, 0, stream>>>(yb, WoT, out);
}

// Round 10
// 176.232 us; speedup vs baseline: 1.0229x; 1.0169x over previous
//
#include <hip/hip_runtime.h>
#include <hip/hip_bf16.h>

// Rounds 0-20 summary: fp32 inputs (inline detector), fp32 out, bf16 MFMA.
// R10: loads just before __syncthreads are DEFEATED (vmcnt(0) drain) unless
// issued a full compute-phase earlier (R18). R12: swapped-QK attn, lane-
// local softmax, exp2-domain, rescale-skip. R13: zero-LDS P path (sigma).
// R14: 512-thr attn, shared staging, complementary pairing. R17: falsified
// barrier-theory; kept vfrag (V pre-laid in frag order -> linear staging).
// R18: vfrag gload16 dbuf + O^T PV (lane-local alpha/l/epilogue) = 176.7
// SESSION BEST. R19 (kfrag bad-XOR + T1 bundle) = 180.3; R20 (kfrag
// corrected-XOR + single-barrier, clean) = 179.2 -> lever retired: both
// attempts <= R18. Floor accounting: ~44us harness fill in timed region +
// ~115-125us kernels (each near its 2-barrier-structure ceiling at these
// small shapes; 8-phase/256^2 template grid-starved at N=2048/1024) +
// ~10us gaps ~= 170-180 measured band (noise +-3).
// R21 (this round): exact revert to R18 — lock in the session best.
#define B_  2
#define T_  2048
#define D_  1024
#define H_  16
#define DH_ 64
#define R_  32
#define BT_ (B_*T_)          // 4096
#define BH_ (B_*H_)          // 32

typedef unsigned short u16;
typedef unsigned int   u32;
typedef __attribute__((ext_vector_type(8))) short bhalf8;   // 8 bf16 = 4 VGPRs
typedef __attribute__((ext_vector_type(4))) float floatx4;  // MFMA C/D

// Workspace layout (bytes). Total ~38 MB.
#define WSB_FLAG  0
#define WSB_XB    256                        // bf16 x     (4096,1024)  8 MB
#define WSB_WCATT (WSB_XB    + 8388608)      // bf16 WcatT (2048,1024)  4 MB
#define WSB_QL    (WSB_WCATT + 4194304)      // bf16 (B,H,T,R)          4 MB
#define WSB_KL    (WSB_QL    + 4194304)      // bf16 (B,H,T,R)          4 MB
#define WSB_VT    (WSB_KL    + 4194304)      // bf16 vfrag (B,H,...)    8 MB
#define WSB_YB    (WSB_VT    + 8388608)      // bf16 y     (B,T,D)      8 MB
#define WSB_WOT   (WSB_YB    + 8388608)      // bf16 WoT   (1024,1024)  2 MB

#define NEG_ -1.0e30f

__device__ __forceinline__ float bfs(u16 s) {
    union { u32 i; float f; } w; w.i = ((u32)s) << 16; return w.f;
}
__device__ __forceinline__ u16 tob(float f) {
    __hip_bfloat16 h = __float2bfloat16(f);   // RNE
    return *(u16*)&h;
}
__device__ __forceinline__ u32 pack2(float a, float b) {
    return (u32)tob(a) | ((u32)tob(b) << 16);
}
// Direct global->LDS staging, 16B/lane. LDS base wave-uniform; HW writes
// base + lane*16. Global address is per-lane.
__device__ __forceinline__ void gload16(const u16* g, u16* l) {
    __builtin_amdgcn_global_load_lds(
        (const __attribute__((address_space(1))) void*)g,
        (__attribute__((address_space(3))) void*)l, 16, 0, 0);
}
// Inline dtype detect (1 = bf16, 0 = fp32) from first 2KB of x.
__device__ __forceinline__ int detect_isbf(const u32* __restrict__ xw, int lane) {
    int hits = 0;
    #pragma unroll
    for (int i = 0; i < 8; ++i) {
        const u32 w = xw[lane + i * 64];
        const u32 h = w & 0xFFFFu;
        const u32 e = (h >> 7) & 0xFFu;
        if (h == 0u || (e >= 100u && e <= 150u)) ++hits;
    }
    #pragma unroll
    for (int off = 32; off; off >>= 1) hits += __shfl_down(hits, off, 64);
    return __shfl(hits, 0, 64) >= 300;
}

// ---------------------------------------------------------------------------
// Kernel P: fused preprocessing (R17).
//  blocks 0..2047   : x -> xb bf16 (8 elems/thread)
//  blocks 2048..2303: transposing convert W_v slice of Wqkv -> WcatT[1024..]
//  blocks 2304..2559: transposing convert W_o -> WoT
//  blocks 2560..2687: fold via MFMA (scale incl 1/sqrt(32)*log2(e))
// ---------------------------------------------------------------------------
__global__ __launch_bounds__(256) void prep_kernel(
    const void* __restrict__ x, u16* __restrict__ xb,
    const void* __restrict__ Wqkv, const void* __restrict__ Wo,
    const void* __restrict__ Wq_lsr, const void* __restrict__ Wk_lsr,
    const void* __restrict__ core,
    u16* __restrict__ WcatT, u16* __restrict__ WoT)
{
    __shared__ __align__(16) u16 Bq[128 * 72];   // fold [n=d][k=dh]; also T-tile
    __shared__ __align__(16) u16 Bk[128 * 72];
    __shared__ __align__(16) u16 Aq[32 * 72];    // fold [m=r][k=dh]
    __shared__ __align__(16) u16 Ak[32 * 72];
    const int tid  = threadIdx.x;
    const int lane = tid & 63;
    const int isbf = detect_isbf((const u32*)x, lane);
    const int blk  = blockIdx.x;
    const int w    = tid >> 6;
    const int n16  = lane & 15;
    const int q4   = lane >> 4;

    if (blk < 2048) {
        const int e = blk * 256 + tid;           // over 524288 (x8 elems)
        if (isbf) {
            ((uint4*)xb)[e] = ((const uint4*)x)[e];
        } else {
            float4 a0 = ((const float4*)x)[2*e];
            float4 a1 = ((const float4*)x)[2*e + 1];
            uint4 o;
            o.x = pack2(a0.x, a0.y); o.y = pack2(a0.z, a0.w);
            o.z = pack2(a1.x, a1.y); o.w = pack2(a1.z, a1.w);
            ((uint4*)xb)[e] = o;
        }
        return;
    }

    if (blk < 2560) {
        // transposing convert, 64x64 tiles (uses Bq as scratch tile)
        int t = blk - 2048;
        const void* src; u16* dst; int srcStride, srcColOff, dstRowOff;
        if (t < 256) { src = Wqkv; dst = WcatT; srcStride = 3*D_; srcColOff = 2*D_; dstRowOff = 1024; }
        else { t -= 256; src = Wo; dst = WoT; srcStride = D_; srcColOff = 0; dstRowOff = 0; }
        const int j0 = (t & 15) * 64;
        const int i0 = (t >> 4) * 64;
        #pragma unroll
        for (int p = 0; p < 2; ++p) {
            const int e = tid + p * 256;
            const int r = e >> 3, ch = e & 7;
            if (isbf) {
                uint4 v = *(const uint4*)((const u16*)src + (size_t)(i0 + r) * srcStride + srcColOff + j0 + ch*8);
                *(uint4*)&Bq[r * 72 + ch*8] = v;
            } else {
                const float* s = (const float*)src + (size_t)(i0 + r) * srcStride + srcColOff + j0 + ch*8;
                float4 a0 = *(const float4*)s;
                float4 a1 = *(const float4*)(s + 4);
                uint4 o;
                o.x = pack2(a0.x, a0.y); o.y = pack2(a0.z, a0.w);
                o.z = pack2(a1.x, a1.y); o.w = pack2(a1.z, a1.w);
                *(uint4*)&Bq[r * 72 + ch*8] = o;
            }
        }
        __syncthreads();
        #pragma unroll
        for (int p = 0; p < 2; ++p) {
            const int e = tid + p * 256;
            const int c = e >> 3, ch = e & 7;
            u16 tmp[8];
            #pragma unroll
            for (int j = 0; j < 8; ++j) tmp[j] = Bq[(ch*8 + j) * 72 + c];
            *(uint4*)(dst + (size_t)(dstRowOff + j0 + c) * D_ + i0 + ch*8) = *(uint4*)tmp;
        }
        return;
    }

    // fold: per head h, Cq(32x1024) = Aq_h^T(32x64) @ Wq_h(64x1024)
    const int fb = blk - 2560;          // 0..127
    const int h  = fb & 15;
    const int d0 = (fb >> 4) * 128;

    #pragma unroll
    for (int p = 0; p < 8; ++p) {
        const int e  = tid + p * 256;
        const int r  = e & 31, dh = e >> 5;
        float aq, ak;
        if (isbf) {
            aq = bfs(((const u16*)Wq_lsr)[(h*DH_ + dh)*R_ + r]);
            ak = bfs(((const u16*)Wk_lsr)[(h*DH_ + dh)*R_ + r]);
        } else {
            aq = ((const float*)Wq_lsr)[(h*DH_ + dh)*R_ + r];
            ak = ((const float*)Wk_lsr)[(h*DH_ + dh)*R_ + r];
        }
        Aq[r * 72 + dh] = tob(aq);
        Ak[r * 72 + dh] = tob(ak);
    }
    #pragma unroll
    for (int p = 0; p < 8; ++p) {
        const int e  = tid + p * 256;      // 0..2047
        const int n  = e >> 4, ch = e & 15;
        if (isbf) {
            uint2 wq = *(const uint2*)((const u16*)Wqkv + (size_t)(d0+n)*(3*D_) + h*DH_ + ch*4);
            uint2 wk = *(const uint2*)((const u16*)Wqkv + (size_t)(d0+n)*(3*D_) + D_ + h*DH_ + ch*4);
            *(uint2*)&Bq[n * 72 + ch*4] = wq;
            *(uint2*)&Bk[n * 72 + ch*4] = wk;
        } else {
            float4 fq = *(const float4*)((const float*)Wqkv + (size_t)(d0+n)*(3*D_) + h*DH_ + ch*4);
            float4 fk = *(const float4*)((const float*)Wqkv + (size_t)(d0+n)*(3*D_) + D_ + h*DH_ + ch*4);
            uint2 oq, ok;
            oq.x = pack2(fq.x, fq.y); oq.y = pack2(fq.z, fq.w);
            ok.x = pack2(fk.x, fk.y); ok.y = pack2(fk.z, fk.w);
            *(uint2*)&Bq[n * 72 + ch*4] = oq;
            *(uint2*)&Bk[n * 72 + ch*4] = ok;
        }
    }
    __syncthreads();

    floatx4 accq[2][2], acck[2][2];
    #pragma unroll
    for (int mi = 0; mi < 2; ++mi)
        #pragma unroll
        for (int ni = 0; ni < 2; ++ni) { accq[mi][ni] = (floatx4)(0.f); acck[mi][ni] = (floatx4)(0.f); }

    #pragma unroll
    for (int kk = 0; kk < 2; ++kk) {
        bhalf8 aqf[2], akf[2], bqf[2], bkf[2];
        #pragma unroll
        for (int mi = 0; mi < 2; ++mi) {
            aqf[mi] = *(const bhalf8*)&Aq[(mi*16 + n16) * 72 + kk*32 + q4*8];
            akf[mi] = *(const bhalf8*)&Ak[(mi*16 + n16) * 72 + kk*32 + q4*8];
        }
        #pragma unroll
        for (int ni = 0; ni < 2; ++ni) {
            bqf[ni] = *(const bhalf8*)&Bq[(w*32 + ni*16 + n16) * 72 + kk*32 + q4*8];
            bkf[ni] = *(const bhalf8*)&Bk[(w*32 + ni*16 + n16) * 72 + kk*32 + q4*8];
        }
        #pragma unroll
        for (int mi = 0; mi < 2; ++mi)
            #pragma unroll
            for (int ni = 0; ni < 2; ++ni) {
                accq[mi][ni] = __builtin_amdgcn_mfma_f32_16x16x32_bf16(aqf[mi], bqf[ni], accq[mi][ni], 0, 0, 0);
                acck[mi][ni] = __builtin_amdgcn_mfma_f32_16x16x32_bf16(akf[mi], bkf[ni], acck[mi][ni], 0, 0, 0);
            }
    }

    const float scale = (float)(0.17677669529663687 * 1.4426950408889634);
    #pragma unroll
    for (int mi = 0; mi < 2; ++mi) {
        #pragma unroll
        for (int rr = 0; rr < 4; ++rr) {
            const int r = mi*16 + q4*4 + rr;
            const float cc = (isbf ? bfs(((const u16*)core)[h*R_ + r])
                                   : ((const float*)core)[h*R_ + r]) * scale;
            #pragma unroll
            for (int ni = 0; ni < 2; ++ni) {
                const int d = d0 + w*32 + ni*16 + n16;
                WcatT[(size_t)(h*R_ + r) * D_ + d]       = tob(accq[mi][ni][rr] * cc);
                WcatT[(size_t)(512 + h*R_ + r) * D_ + d] = tob(acck[mi][ni][rr]);
            }
        }
    }
}

// ---------------------------------------------------------------------------
// Kernel 1 (R17/R18): MFMA gemm1  xb(4096,1024) @ WcatT^T -> ql/kl + vfrag.
// 128x64 tile, BK=64, gload16 staging, 1024 blocks = 4/CU.
// v-epilogue writes vfrag: V in attn's MFMA fragment order,
// vfrag[bh][tile][kc][c2][lane=(qv*16+dh&15)][j], sigma folded in:
// s = 32*kc + 16*j2 + 4*qv + j10 (j = j2*4 + j10).
// ---------------------------------------------------------------------------
__global__ __launch_bounds__(256, 4) void gemm1_mfma(
    const u16* __restrict__ xb, const u16* __restrict__ WcatT,
    u16* __restrict__ ql, u16* __restrict__ kl, u16* __restrict__ vf)
{
    __shared__ __align__(16) u16 As[128 * 64];   // 16384 B, linear
    __shared__ __align__(16) u16 Bs[64 * 64];    //  8192 B, linear
    const int tid  = threadIdx.x;
    const int lane = tid & 63;
    const int w    = tid >> 6;
    const int n16  = lane & 15;
    const int q4   = lane >> 4;
    const int wx   = w & 1;          // n-half (32 cols)
    const int wy   = w >> 1;         // m-half (64 rows)
    const int bm   = blockIdx.y * 128;
    const int bn   = blockIdx.x * 64;
    const int lrow = lane >> 3;          // 0..7: row within 8-row stripe
    const int lcol = (lane & 7) * 8;     // u16 col within 64-col row

    floatx4 acc[4][2];
    #pragma unroll
    for (int i = 0; i < 4; ++i)
        #pragma unroll
        for (int j = 0; j < 2; ++j) acc[i][j] = (floatx4)(0.f);

    for (int kt = 0; kt < D_; kt += 64) {
        #pragma unroll
        for (int i = 0; i < 4; ++i) {
            const int r0 = w*32 + i*8;
            gload16(xb + (size_t)(bm + r0 + lrow) * D_ + kt + lcol, &As[r0 * 64]);
        }
        #pragma unroll
        for (int i = 0; i < 2; ++i) {
            const int r0 = w*16 + i*8;
            gload16(WcatT + (size_t)(bn + r0 + lrow) * D_ + kt + lcol, &Bs[r0 * 64]);
        }
        __syncthreads();
        #pragma unroll
        for (int kk = 0; kk < 2; ++kk) {
            bhalf8 a[4], b[2];
            #pragma unroll
            for (int mi = 0; mi < 4; ++mi)
                a[mi] = *(const bhalf8*)&As[(wy*64 + mi*16 + n16) * 64 + kk*32 + q4*8];
            #pragma unroll
            for (int ni = 0; ni < 2; ++ni)
                b[ni] = *(const bhalf8*)&Bs[(wx*32 + ni*16 + n16) * 64 + kk*32 + q4*8];
            #pragma unroll
            for (int mi = 0; mi < 4; ++mi)
                #pragma unroll
                for (int ni = 0; ni < 2; ++ni)
                    acc[mi][ni] = __builtin_amdgcn_mfma_f32_16x16x32_bf16(
                        a[mi], b[ni], acc[mi][ni], 0, 0, 0);
        }
        __syncthreads();
    }

    if (bn < 1024) {
        #pragma unroll
        for (int mi = 0; mi < 4; ++mi) {
            #pragma unroll
            for (int rr = 0; rr < 4; ++rr) {
                const int row = bm + wy*64 + mi*16 + q4*4 + rr;
                const int b   = row >> 11;
                const int t   = row & (T_ - 1);
                #pragma unroll
                for (int ni = 0; ni < 2; ++ni) {
                    const int col = bn + wx*32 + ni*16 + n16;
                    const u16 val = tob(acc[mi][ni][rr]);
                    if (col < 512) {
                        const int h = col >> 5, r = col & 31;
                        ql[((size_t)(b*H_ + h)*T_ + t)*R_ + r] = val;
                    } else {
                        const int c = col - 512; const int h = c >> 5, r = c & 31;
                        kl[((size_t)(b*H_ + h)*T_ + t)*R_ + r] = val;
                    }
                }
            }
        }
    } else {
        // v -> vfrag (attn fragment order). Thread owns V[t..t+3][dh].
        #pragma unroll
        for (int mi = 0; mi < 4; ++mi) {
            const int row0 = bm + wy*64 + mi*16 + q4*4;   // multiple of 4
            const int b  = row0 >> 11;
            const int t  = row0 & (T_ - 1);
            const int tile = t >> 7;
            const int sl   = t & 127;                     // sl % 4 == 0
            const int kc   = sl >> 5;
            const int j2   = (sl >> 4) & 1;
            const int qv   = (sl >> 2) & 3;
            #pragma unroll
            for (int ni = 0; ni < 2; ++ni) {
                const int c  = bn - 1024 + wx*32 + ni*16 + n16;  // 0..1023
                const int h  = c >> 6, dh = c & 63;
                const int bh = b*H_ + h;
                const int c2 = dh >> 4;
                const int lv = qv*16 + (dh & 15);
                u16* dst = vf + ((((size_t)bh*16 + tile)*4 + kc)*4 + c2)*512
                              + lv*8 + j2*4;
                uint2 o;
                o.x = pack2(acc[mi][ni][0], acc[mi][ni][1]);
                o.y = pack2(acc[mi][ni][2], acc[mi][ni][3]);
                *(uint2*)dst = o;
            }
        }
    }
}

// ---------------------------------------------------------------------------
// softmax update, one q-row per lane. R18: alpha/l fully lane-local
// (O^T PV makes O columns = lane's own q) — no broadcast shuffles.
// ---------------------------------------------------------------------------
__device__ __forceinline__ void softmax_update(
    floatx4 (&Sc)[8], float &mrow, float &lrow, floatx4 (&O)[4])
{
    float cmax[8];
    #pragma unroll
    for (int c = 0; c < 8; ++c)
        cmax[c] = fmaxf(fmaxf(Sc[c][0], Sc[c][1]), fmaxf(Sc[c][2], Sc[c][3]));
    float rmax = fmaxf(fmaxf(fmaxf(cmax[0], cmax[1]), fmaxf(cmax[2], cmax[3])),
                       fmaxf(fmaxf(cmax[4], cmax[5]), fmaxf(cmax[6], cmax[7])));
    rmax = fmaxf(rmax, __shfl_xor(rmax, 16, 64));
    rmax = fmaxf(rmax, __shfl_xor(rmax, 32, 64));

    const float mn = fmaxf(mrow, rmax);
    const int norescale = __all(rmax <= mrow);     // exact: alpha == 1

    float csum[8];
    #pragma unroll
    for (int c = 0; c < 8; ++c) {
        #pragma unroll
        for (int r = 0; r < 4; ++r)
            Sc[c][r] = __builtin_amdgcn_exp2f(Sc[c][r] - mn);
        csum[c] = (Sc[c][0] + Sc[c][1]) + (Sc[c][2] + Sc[c][3]);
    }
    float rsum = ((csum[0] + csum[1]) + (csum[2] + csum[3]))
               + ((csum[4] + csum[5]) + (csum[6] + csum[7]));
    rsum += __shfl_xor(rsum, 16, 64);
    rsum += __shfl_xor(rsum, 32, 64);

    if (norescale) {
        lrow += rsum;                              // mn == mrow exactly
    } else {
        const float alpha = __builtin_amdgcn_exp2f(mrow - mn);
        mrow = mn;
        lrow = lrow * alpha + rsum;
        #pragma unroll
        for (int c2 = 0; c2 < 4; ++c2)
            #pragma unroll
            for (int r = 0; r < 4; ++r) O[c2][r] *= alpha;
    }
}

// ---------------------------------------------------------------------------
// Kernel 2 (R18): swapped-QK flash attention, 512-thr blocks, 128-row
// q-tiles, complementary pairing. V staged via gload16 into double-buffered
// LINEAR vsT (vfrag order, sigma pre-applied); gload for tile it+1 issued
// after the post-staging barrier -> latency hidden under compute (R10-safe).
// PV computes O^T = mfma(V-frag, P-frag): O cols = q = n16 -> alpha/l/
// epilogue lane-local. kls padded (2-way max); vsT reads lane-linear.
// ---------------------------------------------------------------------------
__global__ __launch_bounds__(512, 4) void attn_kernel(
    const u16* __restrict__ ql, const u16* __restrict__ kl,
    const u16* __restrict__ vf, u16* __restrict__ y)
{
    __shared__ __align__(16) u16 kls[128 * 40];      // 10240 B, padded
    __shared__ __align__(16) u16 vsT[2][8192];       // 32768 B, linear dbuf

    const int tid  = threadIdx.x;
    const int lane = tid & 63;
    const int w    = tid >> 6;               // 0..7
    const int n16  = lane & 15;
    const int q4   = lane >> 4;
    const int bh   = blockIdx.x;
    const int by   = blockIdx.y;             // 0..15
    const int qt2  = (by < 8) ? (15 - by) : (by - 8);  // complementary pairs
    const int t0   = qt2 * 128;
    const int nt   = qt2 + 1;                // # of 128-wide s-tiles

    // Q fragment = B-operand of swapped QK^T; loads directly in frag layout.
    const u16* qlb = ql + (size_t)bh * T_ * R_;
    const bhalf8 aq = *(const bhalf8*)(qlb + (size_t)(t0 + w*16 + n16) * R_ + q4*8);

    const u16* klb = kl + (size_t)bh * T_ * R_;
    const u16* vfb = vf + (size_t)bh * 131072;   // 16 tiles * 8192 u16
    const int rk = tid >> 2, ck = (tid & 3) * 8; // kls: 128 rows x 32 cols

    // prologue: K(0) into regs, V(0) gloads into buf 0
    uint4 kc0 = *(const uint4*)(klb + (size_t)rk * R_ + ck);
    uint4 kn0 = kc0;
    gload16(vfb + (size_t)(w*2    ) * 512 + lane*8, &vsT[0][(w*2    ) * 512]);
    gload16(vfb + (size_t)(w*2 + 1) * 512 + lane*8, &vsT[0][(w*2 + 1) * 512]);

    float mrow = NEG_, lrow = 0.f;           // one q-row per lane
    floatx4 O[4];
    #pragma unroll
    for (int c = 0; c < 4; ++c) O[c] = (floatx4)(0.f);

    for (int it = 0; it < nt; ++it) {
        const int cur = it & 1;
        __syncthreads();                     // waves done with prior LDS
        *(uint4*)&kls[rk * 40 + ck] = kc0;
        __syncthreads();                     // drains V(it) gloads (issued
                                             // one compute-phase ago) + kls
        if (it + 1 < nt) {
            // issue NEXT tile's V gloads + K reg prefetch NOW: their
            // latency hides under this tile's compute (R10-safe: the next
            // barrier that drains them is one full compute-phase away).
            const u16* vnb = vfb + (size_t)(it + 1) * 8192;
            gload16(vnb + (size_t)(w*2    ) * 512 + lane*8, &vsT[cur ^ 1][(w*2    ) * 512]);
            gload16(vnb + (size_t)(w*2 + 1) * 512 + lane*8, &vsT[cur ^ 1][(w*2 + 1) * 512]);
            kn0 = *(const uint4*)(klb + (size_t)((it+1)*128 + rk) * R_ + ck);
        }

        // S^T: A = K-frag (m=s), B = Q-frag (n=q). Lane: q=n16, s=16c+4q4+r.
        floatx4 Sc[8];
        #pragma unroll
        for (int c = 0; c < 8; ++c) {
            bhalf8 ak = *(const bhalf8*)&kls[(16*c + n16) * 40 + q4*8];
            Sc[c] = __builtin_amdgcn_mfma_f32_16x16x32_bf16(ak, aq, (floatx4)(0.f), 0, 0, 0);
        }

        if (it == nt - 1) {
            const int tq = w*16 + n16;                 // local q row (0..127)
            #pragma unroll
            for (int c = 0; c < 8; ++c) {
                const int sb = 16*c + 4*q4;            // local s base (s0==t0)
                #pragma unroll
                for (int r = 0; r < 4; ++r)
                    if (sb + r > tq) Sc[c][r] = NEG_;
            }
        }

        softmax_update(Sc, mrow, lrow, O);

        // PV (O^T): A = V-frag from vsT (lane-linear b128), B = P-frag
        // packed from lane's own Sc (sigma order, R13). O cols = q = n16.
        const u16* vt = &vsT[cur][lane * 8];
        #pragma unroll
        for (int kc = 0; kc < 4; ++kc) {
            union { u32 wd[4]; bhalf8 v; } pu;
            pu.wd[0] = pack2(Sc[2*kc    ][0], Sc[2*kc    ][1]);
            pu.wd[1] = pack2(Sc[2*kc    ][2], Sc[2*kc    ][3]);
            pu.wd[2] = pack2(Sc[2*kc + 1][0], Sc[2*kc + 1][1]);
            pu.wd[3] = pack2(Sc[2*kc + 1][2], Sc[2*kc + 1][3]);
            const bhalf8 pa = pu.v;
            #pragma unroll
            for (int c2 = 0; c2 < 4; ++c2) {
                bhalf8 bv = *(const bhalf8*)(vt + (size_t)(kc*4 + c2) * 512);
                O[c2] = __builtin_amdgcn_mfma_f32_16x16x32_bf16(bv, pa, O[c2], 0, 0, 0);
            }
        }

        kc0 = kn0;
    }

    // Epilogue: fully lane-local. Lane holds O^T[dh = 16c2+4q4+rr][q = n16].
    const int b = bh >> 4, h = bh & 15;
    const float rl = 1.0f / lrow;
    const int t = t0 + w*16 + n16;
    u16* yr = y + ((size_t)b * T_ + t) * D_ + h * DH_;
    #pragma unroll
    for (int c2 = 0; c2 < 4; ++c2) {
        uint2 o;
        o.x = pack2(O[c2][0] * rl, O[c2][1] * rl);
        o.y = pack2(O[c2][2] * rl, O[c2][3] * rl);
        *(uint2*)(yr + 16*c2 + 4*q4) = o;
    }
}

// ---------------------------------------------------------------------------
// Kernel 3 (R16): MFMA out-gemm  yb(4096,1024) @ WoT^T -> out fp32.
// 64x64 tile, gload16 staging. Grid (16,64) = 1024 blocks = 4/CU.
// ---------------------------------------------------------------------------
__global__ __launch_bounds__(256, 4) void out_gemm_mfma(
    const u16* __restrict__ yb, const u16* __restrict__ WoT,
    float* __restrict__ out)
{
    __shared__ __align__(16) u16 As[64 * 64];   // 8192 B, linear
    __shared__ __align__(16) u16 Bs[64 * 64];   // 8192 B, linear
    const int tid  = threadIdx.x;
    const int lane = tid & 63;
    const int w    = tid >> 6;
    const int n16  = lane & 15;
    const int q4   = lane >> 4;
    const int wx   = w & 1;          // n-half (32 cols)
    const int wy   = w >> 1;         // m-half (32 rows)
    const int bm   = blockIdx.y * 64;
    const int bn   = blockIdx.x * 64;
    const int lrow = lane >> 3;
    const int lcol = (lane & 7) * 8;

    floatx4 acc[2][2];
    #pragma unroll
    for (int i = 0; i < 2; ++i)
        #pragma unroll
        for (int j = 0; j < 2; ++j) acc[i][j] = (floatx4)(0.f);

    for (int kt = 0; kt < D_; kt += 64) {
        #pragma unroll
        for (int i = 0; i < 2; ++i) {
            const int r0 = w*16 + i*8;
            gload16(yb  + (size_t)(bm + r0 + lrow) * D_ + kt + lcol, &As[r0 * 64]);
            gload16(WoT + (size_t)(bn + r0 + lrow) * D_ + kt + lcol, &Bs[r0 * 64]);
        }
        __syncthreads();
        #pragma unroll
        for (int kk = 0; kk < 2; ++kk) {
            bhalf8 a[2], b[2];
            #pragma unroll
            for (int mi = 0; mi < 2; ++mi)
                a[mi] = *(const bhalf8*)&As[(wy*32 + mi*16 + n16) * 64 + kk*32 + q4*8];
            #pragma unroll
            for (int ni = 0; ni < 2; ++ni)
                b[ni] = *(const bhalf8*)&Bs[(wx*32 + ni*16 + n16) * 64 + kk*32 + q4*8];
            #pragma unroll
            for (int mi = 0; mi < 2; ++mi)
                #pragma unroll
                for (int ni = 0; ni < 2; ++ni)
                    acc[mi][ni] = __builtin_amdgcn_mfma_f32_16x16x32_bf16(
                        a[mi], b[ni], acc[mi][ni], 0, 0, 0);
        }
        __syncthreads();
    }

    #pragma unroll
    for (int mi = 0; mi < 2; ++mi) {
        #pragma unroll
        for (int rr = 0; rr < 4; ++rr) {
            const int row = bm + wy*32 + mi*16 + q4*4 + rr;
            #pragma unroll
            for (int ni = 0; ni < 2; ++ni) {
                const int col = bn + wx*32 + ni*16 + n16;
                out[(size_t)row * D_ + col] = acc[mi][ni][rr];
            }
        }
    }
}

// ---------------------------------------------------------------------------
extern "C" void kernel_launch(void* const* d_in, const int* in_sizes, int n_in,
                              void* d_out, int out_size, void* d_ws, size_t ws_size,
                              hipStream_t stream)
{
    (void)out_size; (void)ws_size;
    const void* in_x = nullptr; const void* in_wqkv = nullptr;
    const void* in_wq = nullptr; const void* in_wk = nullptr;
    const void* in_core = nullptr; const void* in_wo = nullptr;
    for (int i = 0; i < n_in; ++i) {
        const int s = in_sizes[i];
        if      (s == BT_*D_)     { if (!in_x)    in_x    = d_in[i]; }
        else if (s == D_*3*D_)    { if (!in_wqkv) in_wqkv = d_in[i]; }
        else if (s == H_*DH_*R_)  { if (!in_wq)   in_wq   = d_in[i]; else if (!in_wk) in_wk = d_in[i]; }
        else if (s == H_*R_)      { if (!in_core) in_core = d_in[i]; }
        else if (s == D_*D_)      { if (!in_wo)   in_wo   = d_in[i]; }
    }
    if (!in_x)    in_x    = d_in[0];
    if (!in_wqkv) in_wqkv = d_in[1];
    if (!in_wq)   in_wq   = d_in[2];
    if (!in_wk)   in_wk   = d_in[3];
    if (!in_core) in_core = d_in[4];
    if (!in_wo)   in_wo   = d_in[5];

    float* out = (float*)d_out;

    char* ws    = (char*)d_ws;
    u16*  xb    = (u16*)(ws + WSB_XB);
    u16*  WcatT = (u16*)(ws + WSB_WCATT);
    u16*  ql    = (u16*)(ws + WSB_QL);
    u16*  kl    = (u16*)(ws + WSB_KL);
    u16*  vf    = (u16*)(ws + WSB_VT);
    u16*  yb    = (u16*)(ws + WSB_YB);
    u16*  WoT   = (u16*)(ws + WSB_WOT);

    prep_kernel<<<2688, 256, 0, stream>>>(in_x, xb, in_wqkv, in_wo,
                                          in_wq, in_wk, in_core, WcatT, WoT);
    gemm1_mfma<<<dim3(32, 32), 256, 0, stream>>>(xb, WcatT, ql, kl, vf);
    attn_kernel<<<dim3(32, 16), 512, 0, stream>>>(ql, kl, vf, yb);
    out_gemm_mfma<<<dim3(16, 64), 256, 0, stream>>>(yb, WoT, out);
}